// Round 8
// baseline (395.729 us; speedup 1.0000x reference)
//
#include <hip/hip_runtime.h>
#include <math.h>

#define SUBS 20
#define TAPS 201
#define ENO 2000
#define INO 500
#define TDATA 20000

typedef __bf16 bf16x8 __attribute__((ext_vector_type(8)));
typedef float f32x4 __attribute__((ext_vector_type(4)));

#define WGE_STRIDE 2048
#define WGI_STRIDE 512

// workspace byte offsets (ws is ~640 MB; ~132 MB used)
#define WGE_OFF  0ull                    // ushort[64*2048] bf16 weights (E)
#define WGI_OFF  262144ull               // ushort[64*512]  bf16 weights (I)
#define KERN_OFF 327680ull               // float[40*201]   synapse kernels
#define INE_OFF  360448ull               // float[60*20000] E partial chunk0
#define INI_OFF  (INE_OFF + 4800000ull)  // float[60*20000] I (full K)
#define P1_OFF   (INI_OFF + 4800000ull)  // float[60*20000] E partial chunk1
#define P2_OFF   (P1_OFF  + 4800000ull)  // float[60*20000] E partial chunk2
#define P3_OFF   (P2_OFF  + 4800000ull)  // float[60*20000] E partial chunk3
#define SYN_OFF  (P3_OFF  + 4800000ull)  // float[60*20000] syn_in (no alias)
#define AE_OFF   29360128ull             // ushort[20000*2048] bf16 S_e (pad 48)
#define AI_OFF   111280128ull            // ushort[20000*512]  bf16 S_i (pad 12)

__device__ __forceinline__ unsigned short f2bf(float f) {
  union { float f; unsigned int u; } c; c.f = f;
  unsigned int u = c.u;
  return (unsigned short)((u + 0x7FFFu + ((u >> 16) & 1u)) >> 16);  // RTNE
}

__device__ __forceinline__ ushort4 cvt4(float4 f) {
  ushort4 q; q.x = f2bf(f.x); q.y = f2bf(f.y);
  q.z = f2bf(f.z); q.w = f2bf(f.w); return q;
}

__device__ __forceinline__ float fast_tanh(float x) {
  const float ax = fabsf(x);
  const float e  = __expf(2.f * ax);     // e=inf -> t=1 (saturation) is exact
  const float t  = 1.f - 2.f / (e + 1.f);
  return copysignf(t, x);
}

// ---------------------------------------------------------------------------
// K1: per-column prep (theta, hard/soft/softb) + kern filters + weight pads
// ---------------------------------------------------------------------------
__global__ __launch_bounds__(256) void prep_kernel(
    const float* __restrict__ u, const float* __restrict__ v,
    const float* __restrict__ C_log, const float* __restrict__ W_syn,
    const float* __restrict__ Tau_syn, const float* __restrict__ Delta_syn,
    float* __restrict__ out,
    unsigned short* __restrict__ wge, unsigned short* __restrict__ wgi,
    float* __restrict__ kern)
{
  if (blockIdx.x < 10) {
    const int n = blockIdx.x * 256 + threadIdx.x;
    if (n >= 2500) return;
    float x[SUBS], theta[SUBS], rebar[SUBS];
    float mx = -1e30f;
#pragma unroll
    for (int s = 0; s < SUBS; ++s) { x[s] = C_log[s*2500 + n]; mx = fmaxf(mx, x[s]); }
    float sum = 0.f;
#pragma unroll
    for (int s = 0; s < SUBS; ++s) { theta[s] = __expf(x[s] - mx); sum += theta[s]; }
    const float inv = 1.f / sum;
    int idx = 0; float best = -1e30f;
#pragma unroll
    for (int s = 0; s < SUBS; ++s) {
      theta[s] *= inv;
      out[60000 + s*2500 + n] = theta[s];
      const float uu = u[s*2500 + n];
      const float r = __logf(theta[s]) - __logf(-__logf(uu));
      rebar[s] = r;
      if (r > best) { best = r; idx = s; }   // first-wins strict >
    }
    const float lvk = __logf(v[idx*2500 + n]);
#pragma unroll
    for (int s = 0; s < SUBS; ++s) {
      const float hz = (s == idx) ? 1.f : 0.f;
      const float sz = 1.f / (1.f + __expf(-2.f * rebar[s])) + 1e-9f;
      const float vv = v[s*2500 + n];
      const float zb = (s == idx) ? (-__logf(-__logf(vv)))
                                  : (-__logf(-__logf(vv) / theta[s] - lvk));
      const float szb = 1.f / (1.f + __expf(-2.f * zb)) + 1e-9f;
      out[110000 + s*2500 + n] = hz;
      out[160000 + s*2500 + n] = sz;
      out[210000 + s*2500 + n] = szb;
      if (n < ENO) {
        wge[(s     )*WGE_STRIDE + n] = f2bf(hz);
        wge[(20 + s)*WGE_STRIDE + n] = f2bf(sz);
        wge[(40 + s)*WGE_STRIDE + n] = f2bf(szb);
      } else {
        const int k = n - ENO;
        wgi[(s     )*WGI_STRIDE + k] = f2bf(hz);
        wgi[(20 + s)*WGI_STRIDE + k] = f2bf(sz);
        wgi[(40 + s)*WGI_STRIDE + k] = f2bf(szb);
      }
    }
  } else {
    const int tid = threadIdx.x;
    for (int i = tid; i < 40*TAPS; i += 256) {
      const int ch = i / TAPS, m = i - ch*TAPS;
      const float dl  = __expf(Delta_syn[ch]);
      const float tau = __expf(Tau_syn[ch]);
      const float t  = fmaxf((float)m - dl, 0.f);
      const float tt = t / tau;
      kern[i] = tt * __expf(-tt) * W_syn[ch];
    }
    // zero the padded weight regions (ws is poisoned 0xAA every launch)
    for (int i = tid; i < 4*2048; i += 256) wge[(60 + (i >> 11))*WGE_STRIDE + (i & 2047)] = 0;
    for (int i = tid; i < 60*48;  i += 256) wge[(i / 48)*WGE_STRIDE + 2000 + (i % 48)] = 0;
    for (int i = tid; i < 4*512;  i += 256) wgi[(60 + (i >> 9))*WGI_STRIDE + (i & 511)] = 0;
    for (int i = tid; i < 60*12;  i += 256) wgi[(i / 12)*WGI_STRIDE + 500 + (i % 12)] = 0;
  }
}

// ---------------------------------------------------------------------------
// K2a: pure streaming convert S (fp32, d_in) -> padded bf16 A' (d_ws).
//      Shape-identical to the proven ~6.3 TB/s copy loops: per-wave 2KB
//      contiguous reads, sequential writes, no LDS/MFMA/waits. DIAGNOSTIC:
//      its achieved BW separates "d_in read-path anomaly" from "gemm
//      structure" as the cause of the 100us invariant.
//      E: rows padded 2000->2048 with zeros; I: 500->512 with zeros.
// ---------------------------------------------------------------------------
__global__ __launch_bounds__(256) void a2bf_kernel(
    const float* __restrict__ S_e, const float* __restrict__ S_i,
    unsigned short* __restrict__ ae, unsigned short* __restrict__ ai)
{
  const int b   = blockIdx.x;
  const int tid = threadIdx.x;
  if (b < 2500) {                       // E: 8 rows per WG (64KB contiguous)
    const int r0 = b * 8;
    const int k0 = tid * 8;             // 0..2040
#pragma unroll
    for (int r = 0; r < 8; ++r) {
      const int row = r0 + r;
      unsigned short* dst = ae + (size_t)row * 2048 + k0;
      if (k0 < 2000) {                  // threads 0..249 (1992..1999 last)
        const float* src = S_e + (size_t)row * 2000 + k0;
        const float4 f0 = *(const float4*)(src);
        const float4 f1 = *(const float4*)(src + 4);
        *(ushort4*)(dst)     = cvt4(f0);
        *(ushort4*)(dst + 4) = cvt4(f1);
      } else {                          // pad 2000..2047
        *(ushort4*)(dst)     = make_ushort4(0,0,0,0);
        *(ushort4*)(dst + 4) = make_ushort4(0,0,0,0);
      }
    }
  } else {                              // I: 32 rows per WG
    const int r0  = (b - 2500) * 32;
    const int rw  = tid >> 6;           // wave -> row-within-group
    const int k0  = (tid & 63) * 8;     // 0..504
#pragma unroll
    for (int g = 0; g < 8; ++g) {
      const int row = r0 + g*4 + rw;
      unsigned short* dst = ai + (size_t)row * 512 + k0;
      if (k0 + 8 <= INO) {              // k0 <= 488: full 8
        const float* src = S_i + (size_t)row * INO + k0;
        const float4 f0 = *(const float4*)(src);
        const float4 f1 = *(const float4*)(src + 4);
        *(ushort4*)(dst)     = cvt4(f0);
        *(ushort4*)(dst + 4) = cvt4(f1);
      } else if (k0 < INO) {            // k0 == 496: 4 valid + 4 pad
        const float* src = S_i + (size_t)row * INO + k0;
        const float4 f0 = *(const float4*)(src);
        *(ushort4*)(dst)     = cvt4(f0);
        *(ushort4*)(dst + 4) = make_ushort4(0,0,0,0);
      } else {                          // k0 == 504: pad
        *(ushort4*)(dst)     = make_ushort4(0,0,0,0);
        *(ushort4*)(dst + 4) = make_ushort4(0,0,0,0);
      }
    }
  }
}

// ---------------------------------------------------------------------------
// K2b: bf16 MFMA GEMM reading compact A' (freshly written -> L2/L3-warm).
//      R7's proven compute + asm-load machinery; staging is now 16 loads of
//      1KB contiguous bf16 (one per row, no cvt, no k-clamp). Wave-private
//      LDS, zero barriers, counted vmcnt only.
//      grid = (313, 5); y: 0..3 = E k-quarters -> {in_e,P1,P2,P3}; 4 = I.
// ---------------------------------------------------------------------------
__device__ __forceinline__ void gl16(float4& d, const void* p) {
  asm volatile("global_load_dwordx4 %0, %1, off"
               : "=&v"(d) : "v"(p) : "memory");
}

#define MFMA_B16 __builtin_amdgcn_mfma_f32_16x16x32_bf16
#define BC8(x) __builtin_bit_cast(bf16x8, x)

__global__ __launch_bounds__(256) void gemm_kernel(
    const unsigned short* __restrict__ ae, const unsigned short* __restrict__ ai,
    const unsigned short* __restrict__ wge, const unsigned short* __restrict__ wgi,
    float* __restrict__ in_e, float* __restrict__ in_i,
    float* __restrict__ P1, float* __restrict__ P2, float* __restrict__ P3)
{
  __shared__ unsigned short Alds[4][16][520];   // wave-private, 66.5 KB
  const int tid  = threadIdx.x;
  const int wave = tid >> 6;
  const int lane = tid & 63;
  const int m16  = lane & 15;
  const int quad = lane >> 4;
  const int t0   = blockIdx.x * 64;
  const int cy   = blockIdx.y;
  const bool isE = (cy < 4);

  const unsigned short* A = isE ? ae : ai;
  const unsigned short* Wg = isE ? wge : wgi;
  float* outp = (cy == 0) ? in_e : (cy == 1) ? P1 : (cy == 2) ? P2
              : (cy == 3) ? P3   : in_i;
  const int Astride = isE ? 2048 : 512;
  const int Wstride = isE ? WGE_STRIDE : WGI_STRIDE;
  const int k_base  = isE ? cy * 512 : 0;

  const int rbase = t0 + wave*16;
  // per-row source: 1KB contiguous (64 lanes x 16B), row-clamped at M tail
#define AROW(R) (A + (size_t)((rbase + (R) < TDATA) ? rbase + (R) : TDATA - 1) \
                     * Astride + k_base + lane*8)

  // B fragment row pointers (channel rows j*16 + m16), zero-padded buffers
  const unsigned short* B0 = Wg + (size_t)(m16     ) * Wstride;
  const unsigned short* B1 = Wg + (size_t)(m16 + 16) * Wstride;
  const unsigned short* B2 = Wg + (size_t)(m16 + 32) * Wstride;
  const unsigned short* B3 = Wg + (size_t)(m16 + 48) * Wstride;

#define WAITN(N) do {                                                   \
    asm volatile("s_waitcnt vmcnt(" #N ")" ::: "memory");               \
    __builtin_amdgcn_sched_barrier(0);                                  \
  } while (0)

  // ---- staging: 16 x 1KB loads (whole 512-k quarter), grouped waits ----
  {
    float4 g0,g1,g2,g3,g4,g5,g6,g7,g8,g9,g10,g11,g12,g13,g14,g15;
    gl16(g0,  AROW(0));  gl16(g1,  AROW(1));
    gl16(g2,  AROW(2));  gl16(g3,  AROW(3));
    gl16(g4,  AROW(4));  gl16(g5,  AROW(5));
    gl16(g6,  AROW(6));  gl16(g7,  AROW(7));
    gl16(g8,  AROW(8));  gl16(g9,  AROW(9));
    gl16(g10, AROW(10)); gl16(g11, AROW(11));
    gl16(g12, AROW(12)); gl16(g13, AROW(13));
    gl16(g14, AROW(14)); gl16(g15, AROW(15));
    WAITN(12);
    *(float4*)&Alds[wave][0][lane*8]  = g0;
    *(float4*)&Alds[wave][1][lane*8]  = g1;
    *(float4*)&Alds[wave][2][lane*8]  = g2;
    *(float4*)&Alds[wave][3][lane*8]  = g3;
    WAITN(8);
    *(float4*)&Alds[wave][4][lane*8]  = g4;
    *(float4*)&Alds[wave][5][lane*8]  = g5;
    *(float4*)&Alds[wave][6][lane*8]  = g6;
    *(float4*)&Alds[wave][7][lane*8]  = g7;
    WAITN(4);
    *(float4*)&Alds[wave][8][lane*8]  = g8;
    *(float4*)&Alds[wave][9][lane*8]  = g9;
    *(float4*)&Alds[wave][10][lane*8] = g10;
    *(float4*)&Alds[wave][11][lane*8] = g11;
    WAITN(0);
    *(float4*)&Alds[wave][12][lane*8] = g12;
    *(float4*)&Alds[wave][13][lane*8] = g13;
    *(float4*)&Alds[wave][14][lane*8] = g14;
    *(float4*)&Alds[wave][15][lane*8] = g15;
  }
#undef AROW

  f32x4 acc0 = {0.f,0.f,0.f,0.f};
  f32x4 acc1 = acc0, acc2 = acc0, acc3 = acc0;

  // ---- compute: 8 steps; B frags via the proven 2-deep asm pipeline,
  //      A frags from wave-private LDS (bf16) ----
#define ISSUE_B(ST, Q0,Q1,Q2,Q3,Q4,Q5,Q6,Q7) do {                       \
    const int k0_ = k_base + (ST)*64 + quad*8;                          \
    const int k1_ = k0_ + 32;                                           \
    gl16(Q0, B0 + k0_); gl16(Q1, B1 + k0_);                             \
    gl16(Q2, B2 + k0_); gl16(Q3, B3 + k0_);                             \
    gl16(Q4, B0 + k1_); gl16(Q5, B1 + k1_);                             \
    gl16(Q6, B2 + k1_); gl16(Q7, B3 + k1_);                             \
  } while (0)

#define COMPUTE(ST, Q0,Q1,Q2,Q3,Q4,Q5,Q6,Q7) do {                       \
    const bf16x8 x0 = *(const bf16x8*)&Alds[wave][m16][(ST)*64      + quad*8]; \
    const bf16x8 x1 = *(const bf16x8*)&Alds[wave][m16][(ST)*64 + 32 + quad*8]; \
    acc0 = MFMA_B16(x0, BC8(Q0), acc0, 0, 0, 0);                        \
    acc1 = MFMA_B16(x0, BC8(Q1), acc1, 0, 0, 0);                        \
    acc2 = MFMA_B16(x0, BC8(Q2), acc2, 0, 0, 0);                        \
    acc3 = MFMA_B16(x0, BC8(Q3), acc3, 0, 0, 0);                        \
    acc0 = MFMA_B16(x1, BC8(Q4), acc0, 0, 0, 0);                        \
    acc1 = MFMA_B16(x1, BC8(Q5), acc1, 0, 0, 0);                        \
    acc2 = MFMA_B16(x1, BC8(Q6), acc2, 0, 0, 0);                        \
    acc3 = MFMA_B16(x1, BC8(Q7), acc3, 0, 0, 0);                        \
  } while (0)

  {
    float4 s00,s01,s02,s03,s04,s05,s06,s07;
    float4 s10,s11,s12,s13,s14,s15,s16,s17;
    ISSUE_B(0, s00,s01,s02,s03,s04,s05,s06,s07);
    ISSUE_B(1, s10,s11,s12,s13,s14,s15,s16,s17);
    WAITN(8);
    COMPUTE(0, s00,s01,s02,s03,s04,s05,s06,s07);
    ISSUE_B(2, s00,s01,s02,s03,s04,s05,s06,s07);
    WAITN(8);
    COMPUTE(1, s10,s11,s12,s13,s14,s15,s16,s17);
    ISSUE_B(3, s10,s11,s12,s13,s14,s15,s16,s17);
    WAITN(8);
    COMPUTE(2, s00,s01,s02,s03,s04,s05,s06,s07);
    ISSUE_B(4, s00,s01,s02,s03,s04,s05,s06,s07);
    WAITN(8);
    COMPUTE(3, s10,s11,s12,s13,s14,s15,s16,s17);
    ISSUE_B(5, s10,s11,s12,s13,s14,s15,s16,s17);
    WAITN(8);
    COMPUTE(4, s00,s01,s02,s03,s04,s05,s06,s07);
    ISSUE_B(6, s00,s01,s02,s03,s04,s05,s06,s07);
    WAITN(8);
    COMPUTE(5, s10,s11,s12,s13,s14,s15,s16,s17);
    ISSUE_B(7, s10,s11,s12,s13,s14,s15,s16,s17);
    WAITN(8);
    COMPUTE(6, s00,s01,s02,s03,s04,s05,s06,s07);
    WAITN(0);
    COMPUTE(7, s10,s11,s12,s13,s14,s15,s16,s17);
  }
#undef ISSUE_B
#undef COMPUTE
#undef WAITN

  // epilogue: C/D layout col=m16 -> channel, row=quad*4+r -> t-local
  const int t = t0 + wave*16 + quad*4;
  if (t < TDATA) {
    float* o = outp + t;
    *(float4*)(o + (size_t)(     m16)*TDATA) = *(float4*)&acc0;
    *(float4*)(o + (size_t)(16 + m16)*TDATA) = *(float4*)&acc1;
    *(float4*)(o + (size_t)(32 + m16)*TDATA) = *(float4*)&acc2;
    if (m16 < 12)
      *(float4*)(o + (size_t)(48 + m16)*TDATA) = *(float4*)&acc3;
  }
}

// ---------------------------------------------------------------------------
// K3: 201-tap causal FIR per (var,s), with the split-K reduction fused into
//     the LDS staging: E window = in_e + P1 + P2 + P3, I window = in_i.
// ---------------------------------------------------------------------------
__device__ __forceinline__ int swz(int i) { return i + (i >> 5); }

__global__ __launch_bounds__(256) void conv_kernel(
    const float* __restrict__ in_e, const float* __restrict__ P1,
    const float* __restrict__ P2,  const float* __restrict__ P3,
    const float* __restrict__ in_i,
    const float* __restrict__ kern, float* __restrict__ syn)
{
  __shared__ float Ee[2320];
  __shared__ float Ei[2320];
  const int ch = blockIdx.y;            // var*20 + s
  const int t0 = blockIdx.x * 2048;
  const int s  = ch % SUBS;
  const size_t off = (size_t)ch * TDATA;
  for (int i = threadIdx.x; i < 2248; i += 256) {
    const int g = t0 - 200 + i;
    float e = 0.f, ii = 0.f;
    if (g >= 0 && g < TDATA) {
      e = in_e[off + g] + P1[off + g] + P2[off + g] + P3[off + g];
      ii = in_i[off + g];
    }
    Ee[swz(i)] = e;
    Ei[swz(i)] = ii;
  }
  __syncthreads();
  const float* ke = kern + (size_t)(s*2    ) * TAPS;
  const float* ki = kern + (size_t)(s*2 + 1) * TAPS;
  const int tb = threadIdx.x * 8;
  float acc[8] = {0.f,0.f,0.f,0.f,0.f,0.f,0.f,0.f};
  float we[8], wi[8];
#pragma unroll
  for (int j = 0; j < 8; ++j) {
    we[j] = Ee[swz(tb + 200 + j)];
    wi[j] = Ei[swz(tb + 200 + j)];
  }
#pragma unroll 8
  for (int m = 0; m < TAPS; ++m) {
    const float k0 = ke[m];
    const float k1 = ki[m];
#pragma unroll
    for (int j = 0; j < 8; ++j)
      acc[j] = fmaf(we[j], k0, fmaf(wi[j], k1, acc[j]));
    if (m < TAPS - 1) {
#pragma unroll
      for (int j = 7; j > 0; --j) { we[j] = we[j-1]; wi[j] = wi[j-1]; }
      we[0] = Ee[swz(tb + 199 - m)];
      wi[0] = Ei[swz(tb + 199 - m)];
    }
  }
  const int t = t0 + tb;
  if (t < TDATA) {
    float* o = syn + off + t;
    *(float4*)(o    ) = make_float4(acc[0], acc[1], acc[2], acc[3]);
    *(float4*)(o + 4) = make_float4(acc[4], acc[5], acc[6], acc[7]);
  }
}

// ---------------------------------------------------------------------------
// K4: tanh tree combine -> V outputs
// ---------------------------------------------------------------------------
__global__ __launch_bounds__(256) void tree_kernel(
    const float* __restrict__ syn, const float* __restrict__ W_sub,
    const float* __restrict__ V_o, float* __restrict__ out)
{
  const int t = blockIdx.x * 256 + threadIdx.x;
  const int var = blockIdx.y;
  if (t >= TDATA) return;
  const float* sp = syn + (size_t)var * SUBS * TDATA + t;
  float so[SUBS];
#pragma unroll
  for (int s = SUBS - 1; s >= 0; --s) {
    float val = sp[(size_t)s * TDATA];
    const int c1 = 2*s + 1, c2 = 2*s + 2;
    if (c1 < SUBS) val += so[c1] * W_sub[c1];
    if (c2 < SUBS) val += so[c2] * W_sub[c2];
    so[s] = fast_tanh(val);
  }
  out[(size_t)var * TDATA + t] = so[0] * W_sub[0] + V_o[0];
}

extern "C" void kernel_launch(void* const* d_in, const int* in_sizes, int n_in,
                              void* d_out, int out_size, void* d_ws, size_t ws_size,
                              hipStream_t stream) {
  const float* S_e     = (const float*)d_in[0];
  const float* S_i     = (const float*)d_in[1];
  const float* u       = (const float*)d_in[2];
  const float* v       = (const float*)d_in[3];
  const float* W_syn   = (const float*)d_in[4];
  const float* Tau_syn = (const float*)d_in[5];
  const float* Delta   = (const float*)d_in[6];
  const float* W_sub   = (const float*)d_in[7];
  const float* V_o     = (const float*)d_in[8];
  const float* C_log   = (const float*)d_in[10];   // d_in[9] = Theta, unused
  float* out = (float*)d_out;
  char* ws = (char*)d_ws;
  unsigned short* wge = (unsigned short*)(ws + WGE_OFF);
  unsigned short* wgi = (unsigned short*)(ws + WGI_OFF);
  float* kern = (float*)(ws + KERN_OFF);
  float* in_e = (float*)(ws + INE_OFF);
  float* in_i = (float*)(ws + INI_OFF);
  float* P1   = (float*)(ws + P1_OFF);
  float* P2   = (float*)(ws + P2_OFF);
  float* P3   = (float*)(ws + P3_OFF);
  float* syn  = (float*)(ws + SYN_OFF);
  unsigned short* ae = (unsigned short*)(ws + AE_OFF);
  unsigned short* ai = (unsigned short*)(ws + AI_OFF);

  prep_kernel<<<dim3(11), dim3(256), 0, stream>>>(u, v, C_log, W_syn, Tau_syn,
                                                  Delta, out, wge, wgi, kern);
  a2bf_kernel<<<dim3(3125), dim3(256), 0, stream>>>(S_e, S_i, ae, ai);
  gemm_kernel<<<dim3(313, 5), dim3(256), 0, stream>>>(
      ae, ai, wge, wgi, in_e, in_i, P1, P2, P3);
  conv_kernel<<<dim3(10, 60), dim3(256), 0, stream>>>(in_e, P1, P2, P3, in_i,
                                                      kern, syn);
  tree_kernel<<<dim3(79, 3), dim3(256), 0, stream>>>(syn, W_sub, V_o, out);
}

// Round 10
// 364.519 us; speedup vs baseline: 1.0856x; 1.0856x over previous
//
#include <hip/hip_runtime.h>
#include <math.h>

#define SUBS 20
#define TAPS 201
#define ENO 2000
#define INO 500
#define TDATA 20000

typedef __bf16 bf16x8 __attribute__((ext_vector_type(8)));
typedef float f32x4 __attribute__((ext_vector_type(4)));

#define WGE_STRIDE 2048
#define WGI_STRIDE 512

// workspace byte offsets (ws is ~640 MB per fill counter; 29.2 MB used)
#define WGE_OFF  0ull                    // ushort[64*2048] bf16 weights (E)
#define WGI_OFF  262144ull               // ushort[64*512]  bf16 weights (I)
#define KERN_OFF 327680ull               // float[40*201]   synapse kernels
#define INE_OFF  360448ull               // float[60*20000] E partial chunk0
#define INI_OFF  (INE_OFF + 4800000ull)  // float[60*20000] I (full K)
#define P1_OFF   (INI_OFF + 4800000ull)  // float[60*20000] E partial chunk1
#define P2_OFF   (P1_OFF  + 4800000ull)  // float[60*20000] E partial chunk2
#define P3_OFF   (P2_OFF  + 4800000ull)  // float[60*20000] E partial chunk3
#define SYN_OFF  (P3_OFF  + 4800000ull)  // float[60*20000] syn_in (no alias)

__device__ __forceinline__ unsigned short f2bf(float f) {
  union { float f; unsigned int u; } c; c.f = f;
  unsigned int u = c.u;
  return (unsigned short)((u + 0x7FFFu + ((u >> 16) & 1u)) >> 16);  // RTNE
}

__device__ __forceinline__ float fast_tanh(float x) {
  const float ax = fabsf(x);
  const float e  = __expf(2.f * ax);     // e=inf -> t=1 (saturation) is exact
  const float t  = 1.f - 2.f / (e + 1.f);
  return copysignf(t, x);
}

// ---------------------------------------------------------------------------
// K1: per-column prep (theta, hard/soft/softb) + kern filters + weight pads
// ---------------------------------------------------------------------------
__global__ __launch_bounds__(256) void prep_kernel(
    const float* __restrict__ u, const float* __restrict__ v,
    const float* __restrict__ C_log, const float* __restrict__ W_syn,
    const float* __restrict__ Tau_syn, const float* __restrict__ Delta_syn,
    float* __restrict__ out,
    unsigned short* __restrict__ wge, unsigned short* __restrict__ wgi,
    float* __restrict__ kern)
{
  if (blockIdx.x < 10) {
    const int n = blockIdx.x * 256 + threadIdx.x;
    if (n >= 2500) return;
    float x[SUBS], theta[SUBS], rebar[SUBS];
    float mx = -1e30f;
#pragma unroll
    for (int s = 0; s < SUBS; ++s) { x[s] = C_log[s*2500 + n]; mx = fmaxf(mx, x[s]); }
    float sum = 0.f;
#pragma unroll
    for (int s = 0; s < SUBS; ++s) { theta[s] = __expf(x[s] - mx); sum += theta[s]; }
    const float inv = 1.f / sum;
    int idx = 0; float best = -1e30f;
#pragma unroll
    for (int s = 0; s < SUBS; ++s) {
      theta[s] *= inv;
      out[60000 + s*2500 + n] = theta[s];
      const float uu = u[s*2500 + n];
      const float r = __logf(theta[s]) - __logf(-__logf(uu));
      rebar[s] = r;
      if (r > best) { best = r; idx = s; }   // first-wins strict >
    }
    const float lvk = __logf(v[idx*2500 + n]);
#pragma unroll
    for (int s = 0; s < SUBS; ++s) {
      const float hz = (s == idx) ? 1.f : 0.f;
      const float sz = 1.f / (1.f + __expf(-2.f * rebar[s])) + 1e-9f;
      const float vv = v[s*2500 + n];
      const float zb = (s == idx) ? (-__logf(-__logf(vv)))
                                  : (-__logf(-__logf(vv) / theta[s] - lvk));
      const float szb = 1.f / (1.f + __expf(-2.f * zb)) + 1e-9f;
      out[110000 + s*2500 + n] = hz;
      out[160000 + s*2500 + n] = sz;
      out[210000 + s*2500 + n] = szb;
      if (n < ENO) {
        wge[(s     )*WGE_STRIDE + n] = f2bf(hz);
        wge[(20 + s)*WGE_STRIDE + n] = f2bf(sz);
        wge[(40 + s)*WGE_STRIDE + n] = f2bf(szb);
      } else {
        const int k = n - ENO;
        wgi[(s     )*WGI_STRIDE + k] = f2bf(hz);
        wgi[(20 + s)*WGI_STRIDE + k] = f2bf(sz);
        wgi[(40 + s)*WGI_STRIDE + k] = f2bf(szb);
      }
    }
  } else {
    const int tid = threadIdx.x;
    for (int i = tid; i < 40*TAPS; i += 256) {
      const int ch = i / TAPS, m = i - ch*TAPS;
      const float dl  = __expf(Delta_syn[ch]);
      const float tau = __expf(Tau_syn[ch]);
      const float t  = fmaxf((float)m - dl, 0.f);
      const float tt = t / tau;
      kern[i] = tt * __expf(-tt) * W_syn[ch];
    }
    // zero the padded weight regions (ws is poisoned 0xAA every launch)
    for (int i = tid; i < 4*2048; i += 256) wge[(60 + (i >> 11))*WGE_STRIDE + (i & 2047)] = 0;
    for (int i = tid; i < 60*48;  i += 256) wge[(i / 48)*WGE_STRIDE + 2000 + (i % 48)] = 0;
    for (int i = tid; i < 4*512;  i += 256) wgi[(60 + (i >> 9))*WGI_STRIDE + (i & 511)] = 0;
    for (int i = tid; i < 60*12;  i += 256) wgi[(i / 12)*WGI_STRIDE + 500 + (i % 12)] = 0;
  }
}

// ---------------------------------------------------------------------------
// K2: bf16 MFMA GEMM (R1 structure, best measured 331.99us) + two changes:
//     (1) NON-TEMPORAL A loads (via native ext-vector f32x4 — the builtin
//         rejects HIP_vector_type): S is streamed exactly once, never
//         reused. nt bypasses cache allocation -> no dirty-L3 eviction
//         pressure from the harness's 640MB/launch ws poison competing
//         with the S read stream. Tests the ~2 TB/s read wall that R8's
//         pure-stream experiment exposed.
//     (2) Bijective XCD-chunked blockIdx.x swizzle (m204 formula): each XCD
//         reads a contiguous ~20MB slab of S -> longer DRAM page streams.
//     M=64 / BK=64 / 256 threads, register-prefetch double buffer, split-K.
//     grid = (313, 5); y: 0..3 = E k-quarters -> {in_e,P1,P2,P3}; 4 = I.
// ---------------------------------------------------------------------------
#define LOAD_A(k0, d0, d1, d2, d3) do {                          \
    const int kb_ = (k0) + slotA*16;                             \
    const int c0_ = (kb_ +  4 <= K) ? kb_      : K - 4;          \
    const int c1_ = (kb_ +  8 <= K) ? kb_ +  4 : K - 4;          \
    const int c2_ = (kb_ + 12 <= K) ? kb_ +  8 : K - 4;          \
    const int c3_ = (kb_ + 16 <= K) ? kb_ + 12 : K - 4;          \
    d0 = __builtin_nontemporal_load((const f32x4*)(Arow + c0_)); \
    d1 = __builtin_nontemporal_load((const f32x4*)(Arow + c1_)); \
    d2 = __builtin_nontemporal_load((const f32x4*)(Arow + c2_)); \
    d3 = __builtin_nontemporal_load((const f32x4*)(Arow + c3_)); \
  } while (0)

__global__ __launch_bounds__(256) void gemm_kernel(
    const float* __restrict__ S_e, const float* __restrict__ S_i,
    const unsigned short* __restrict__ wge, const unsigned short* __restrict__ wgi,
    float* __restrict__ in_e, float* __restrict__ in_i,
    float* __restrict__ P1, float* __restrict__ P2, float* __restrict__ P3)
{
  __shared__ unsigned short Alds[64*72];   // [t-row][k] bf16, stride 72
  __shared__ unsigned short Blds[64*72];   // [c-row][k] bf16, stride 72
  const int tid  = threadIdx.x;
  const int wave = tid >> 6;
  const int lane = tid & 63;
  const int m16  = lane & 15;
  const int quad = lane >> 4;
  // bijective XCD-chunked swizzle (nwg=313: q=39, r=1) — each XCD gets a
  // contiguous chunk of t-tiles
  const int nwg  = gridDim.x;
  const int q_   = nwg >> 3, r_ = nwg & 7;
  const int xcd  = blockIdx.x & 7, lid = blockIdx.x >> 3;
  const int bx   = (xcd < r_ ? xcd*(q_+1) : r_*(q_+1) + (xcd-r_)*q_) + lid;
  const int t0   = bx * 64;
  const int cy   = blockIdx.y;
  const bool isE = (cy < 4);

  const float* S = isE ? S_e : S_i;
  const unsigned short* Wg = isE ? wge : wgi;
  float* outp = (cy == 0) ? in_e : (cy == 1) ? P1 : (cy == 2) ? P2
              : (cy == 3) ? P3   : in_i;
  const int K       = isE ? ENO : INO;
  const int Wstride = isE ? WGE_STRIDE : WGI_STRIDE;
  const int k_base  = isE ? cy * 512 : 0;

  // staging maps: 4 threads per row, 16 elems (A: floats, B: shorts) each
  const int rowA  = tid >> 2;          // 0..63
  const int slotA = tid & 3;
  const int tA    = t0 + rowA;
  const float* Arow = S + (size_t)((tA < TDATA) ? tA : TDATA - 1) * K;
  const unsigned short* Brow = Wg + (size_t)rowA * Wstride + slotA*16;

  f32x4 acc0 = {0.f,0.f,0.f,0.f};
  f32x4 acc1 = acc0, acc2 = acc0, acc3 = acc0;

  // prologue: issue step-0 loads
  f32x4 a0, a1, a2, a3, n0, n1, n2, n3;
  uint4 bw0, bw1, nb0, nb1;
  {
    const int k0 = k_base;
    bw0 = *(const uint4*)(Brow + k0);
    bw1 = *(const uint4*)(Brow + k0 + 8);
    LOAD_A(k0, a0, a1, a2, a3);
  }

#pragma unroll
  for (int st = 0; st < 8; ++st) {
    // issue next-step loads first (independent of current regs)
    if (st < 7) {
      const int kn = k_base + (st + 1) * 64;
      nb0 = *(const uint4*)(Brow + kn);
      nb1 = *(const uint4*)(Brow + kn + 8);
      LOAD_A(kn, n0, n1, n2, n3);
    }
    // convert current A regs -> bf16 and stage both tiles
    ushort4 p0, p1, p2, p3;
    p0.x = f2bf(a0[0]); p0.y = f2bf(a0[1]); p0.z = f2bf(a0[2]); p0.w = f2bf(a0[3]);
    p1.x = f2bf(a1[0]); p1.y = f2bf(a1[1]); p1.z = f2bf(a1[2]); p1.w = f2bf(a1[3]);
    p2.x = f2bf(a2[0]); p2.y = f2bf(a2[1]); p2.z = f2bf(a2[2]); p2.w = f2bf(a2[3]);
    p3.x = f2bf(a3[0]); p3.y = f2bf(a3[1]); p3.z = f2bf(a3[2]); p3.w = f2bf(a3[3]);
    unsigned short* adst = &Alds[rowA*72 + slotA*16];
    *(ushort4*)(adst    ) = p0;  *(ushort4*)(adst + 4) = p1;
    *(ushort4*)(adst + 8) = p2;  *(ushort4*)(adst +12) = p3;
    unsigned short* bdst = &Blds[rowA*72 + slotA*16];
    *(uint4*)(bdst    ) = bw0;
    *(uint4*)(bdst + 8) = bw1;
    __syncthreads();
    // compute: 2 k-halves of 32; frag A[m=lane&15][k=quad*8+j]
#pragma unroll
    for (int h = 0; h < 2; ++h) {
      const int kh = h*32 + quad*8;
      const bf16x8 a  = *(const bf16x8*)(&Alds[(wave*16 + m16)*72 + kh]);
      const bf16x8 b0 = *(const bf16x8*)(&Blds[(      m16)*72 + kh]);
      const bf16x8 b1 = *(const bf16x8*)(&Blds[(16 + m16)*72 + kh]);
      const bf16x8 b2 = *(const bf16x8*)(&Blds[(32 + m16)*72 + kh]);
      const bf16x8 b3 = *(const bf16x8*)(&Blds[(48 + m16)*72 + kh]);
      acc0 = __builtin_amdgcn_mfma_f32_16x16x32_bf16(a, b0, acc0, 0, 0, 0);
      acc1 = __builtin_amdgcn_mfma_f32_16x16x32_bf16(a, b1, acc1, 0, 0, 0);
      acc2 = __builtin_amdgcn_mfma_f32_16x16x32_bf16(a, b2, acc2, 0, 0, 0);
      acc3 = __builtin_amdgcn_mfma_f32_16x16x32_bf16(a, b3, acc3, 0, 0, 0);
    }
    __syncthreads();
    // rotate buffers (SSA renames, no runtime indexing)
    a0 = n0; a1 = n1; a2 = n2; a3 = n3;
    bw0 = nb0; bw1 = nb1;
  }
  // epilogue: C/D layout col=m16 -> c, row=quad*4+r -> t-local (wave's 16)
  const int t = t0 + wave*16 + quad*4;
  if (t < TDATA) {
    float* o = outp + t;
    *(float4*)(o + (size_t)(     m16)*TDATA) = *(float4*)&acc0;
    *(float4*)(o + (size_t)(16 + m16)*TDATA) = *(float4*)&acc1;
    *(float4*)(o + (size_t)(32 + m16)*TDATA) = *(float4*)&acc2;
    if (m16 < 12)
      *(float4*)(o + (size_t)(48 + m16)*TDATA) = *(float4*)&acc3;
  }
}

// ---------------------------------------------------------------------------
// K3: 201-tap causal FIR per (var,s), with the split-K reduction fused into
//     the LDS staging: E window = in_e + P1 + P2 + P3, I window = in_i.
// ---------------------------------------------------------------------------
__device__ __forceinline__ int swz(int i) { return i + (i >> 5); }

__global__ __launch_bounds__(256) void conv_kernel(
    const float* __restrict__ in_e, const float* __restrict__ P1,
    const float* __restrict__ P2,  const float* __restrict__ P3,
    const float* __restrict__ in_i,
    const float* __restrict__ kern, float* __restrict__ syn)
{
  __shared__ float Ee[2320];
  __shared__ float Ei[2320];
  const int ch = blockIdx.y;            // var*20 + s
  const int t0 = blockIdx.x * 2048;
  const int s  = ch % SUBS;
  const size_t off = (size_t)ch * TDATA;
  for (int i = threadIdx.x; i < 2248; i += 256) {
    const int g = t0 - 200 + i;
    float e = 0.f, ii = 0.f;
    if (g >= 0 && g < TDATA) {
      e = in_e[off + g] + P1[off + g] + P2[off + g] + P3[off + g];
      ii = in_i[off + g];
    }
    Ee[swz(i)] = e;
    Ei[swz(i)] = ii;
  }
  __syncthreads();
  const float* ke = kern + (size_t)(s*2    ) * TAPS;
  const float* ki = kern + (size_t)(s*2 + 1) * TAPS;
  const int tb = threadIdx.x * 8;
  float acc[8] = {0.f,0.f,0.f,0.f,0.f,0.f,0.f,0.f};
  float we[8], wi[8];
#pragma unroll
  for (int j = 0; j < 8; ++j) {
    we[j] = Ee[swz(tb + 200 + j)];
    wi[j] = Ei[swz(tb + 200 + j)];
  }
#pragma unroll 8
  for (int m = 0; m < TAPS; ++m) {
    const float k0 = ke[m];
    const float k1 = ki[m];
#pragma unroll
    for (int j = 0; j < 8; ++j)
      acc[j] = fmaf(we[j], k0, fmaf(wi[j], k1, acc[j]));
    if (m < TAPS - 1) {
#pragma unroll
      for (int j = 7; j > 0; --j) { we[j] = we[j-1]; wi[j] = wi[j-1]; }
      we[0] = Ee[swz(tb + 199 - m)];
      wi[0] = Ei[swz(tb + 199 - m)];
    }
  }
  const int t = t0 + tb;
  if (t < TDATA) {
    float* o = syn + off + t;
    *(float4*)(o    ) = make_float4(acc[0], acc[1], acc[2], acc[3]);
    *(float4*)(o + 4) = make_float4(acc[4], acc[5], acc[6], acc[7]);
  }
}

// ---------------------------------------------------------------------------
// K4: tanh tree combine -> V outputs
// ---------------------------------------------------------------------------
__global__ __launch_bounds__(256) void tree_kernel(
    const float* __restrict__ syn, const float* __restrict__ W_sub,
    const float* __restrict__ V_o, float* __restrict__ out)
{
  const int t = blockIdx.x * 256 + threadIdx.x;
  const int var = blockIdx.y;
  if (t >= TDATA) return;
  const float* sp = syn + (size_t)var * SUBS * TDATA + t;
  float so[SUBS];
#pragma unroll
  for (int s = SUBS - 1; s >= 0; --s) {
    float val = sp[(size_t)s * TDATA];
    const int c1 = 2*s + 1, c2 = 2*s + 2;
    if (c1 < SUBS) val += so[c1] * W_sub[c1];
    if (c2 < SUBS) val += so[c2] * W_sub[c2];
    so[s] = fast_tanh(val);
  }
  out[(size_t)var * TDATA + t] = so[0] * W_sub[0] + V_o[0];
}

extern "C" void kernel_launch(void* const* d_in, const int* in_sizes, int n_in,
                              void* d_out, int out_size, void* d_ws, size_t ws_size,
                              hipStream_t stream) {
  const float* S_e     = (const float*)d_in[0];
  const float* S_i     = (const float*)d_in[1];
  const float* u       = (const float*)d_in[2];
  const float* v       = (const float*)d_in[3];
  const float* W_syn   = (const float*)d_in[4];
  const float* Tau_syn = (const float*)d_in[5];
  const float* Delta   = (const float*)d_in[6];
  const float* W_sub   = (const float*)d_in[7];
  const float* V_o     = (const float*)d_in[8];
  const float* C_log   = (const float*)d_in[10];   // d_in[9] = Theta, unused
  float* out = (float*)d_out;
  char* ws = (char*)d_ws;
  unsigned short* wge = (unsigned short*)(ws + WGE_OFF);
  unsigned short* wgi = (unsigned short*)(ws + WGI_OFF);
  float* kern = (float*)(ws + KERN_OFF);
  float* in_e = (float*)(ws + INE_OFF);
  float* in_i = (float*)(ws + INI_OFF);
  float* P1   = (float*)(ws + P1_OFF);
  float* P2   = (float*)(ws + P2_OFF);
  float* P3   = (float*)(ws + P3_OFF);
  float* syn  = (float*)(ws + SYN_OFF);

  prep_kernel<<<dim3(11), dim3(256), 0, stream>>>(u, v, C_log, W_syn, Tau_syn,
                                                  Delta, out, wge, wgi, kern);
  gemm_kernel<<<dim3(313, 5), dim3(256), 0, stream>>>(
      S_e, S_i, wge, wgi, in_e, in_i, P1, P2, P3);
  conv_kernel<<<dim3(10, 60), dim3(256), 0, stream>>>(in_e, P1, P2, P3, in_i,
                                                      kern, syn);
  tree_kernel<<<dim3(79, 3), dim3(256), 0, stream>>>(syn, W_sub, V_o, out);
}